// Round 1
// baseline (473.504 us; speedup 1.0000x reference)
//
#include <hip/hip_runtime.h>
#include <hip/hip_bf16.h>

#define B_ 256
#define T_ 400
#define NMELS 80
#define INP 512
#define DEC_ 128
#define LSTM_ 1024
#define PRE 256
#define FILT 32
#define KS 31
#define MAXR 20

typedef float f32x4 __attribute__((ext_vector_type(4)));
typedef short bf16x8 __attribute__((ext_vector_type(8)));

__device__ __forceinline__ short f2bf(float f) {
  union { float f; unsigned u; } v; v.f = f;
  unsigned u = v.u;
  unsigned r = (u + 0x7fffu + ((u >> 16) & 1u)) >> 16;
  return (short)r;
}

__device__ __forceinline__ float sigmoidf_(float x) {
  return 1.f / (1.f + __expf(-x));
}
__device__ __forceinline__ float tanhf_(float x) {
  float e = __expf(2.f * x);
  return 1.f - 2.f / (e + 1.f);
}

// ---------------------------------------------------------------------------
// Generic bf16-MFMA GEMM: out[m, n] = act( sum_k A1[m,k]*W1[n,k]
//                                        + sum_k A2[m,k]*W2[n,k] + b1[n]+b2[n] )
// A: [M][K] f32 row-major, W: [N][K] f32 row-major. M = grid.y*64, N = grid.x*64.
// K arbitrary (zero-padded staging). act: 0=none, 1=relu.
// ---------------------------------------------------------------------------
__global__ __launch_bounds__(256) void gemm_bf16(
    const float* __restrict__ A1, const float* __restrict__ W1, int K1,
    const float* __restrict__ A2, const float* __restrict__ W2, int K2,
    const float* __restrict__ bias1, const float* __restrict__ bias2,
    float* __restrict__ out, int ldo, int act)
{
  __shared__ __align__(16) short sA[64][40];
  __shared__ __align__(16) short sB[64][40];
  const int tid  = threadIdx.x;
  const int lane = tid & 63;
  const int wave = tid >> 6;
  const int wr = (wave >> 1) * 32;
  const int wc = (wave & 1) * 32;
  const int bm = blockIdx.y * 64;
  const int bn = blockIdx.x * 64;
  const int sr = tid >> 2;         // 0..63
  const int sk = (tid & 3) * 8;    // 0,8,16,24
  const int l15 = lane & 15;
  const int kq  = (lane >> 4) * 8;

  f32x4 acc[2][2];
#pragma unroll
  for (int i = 0; i < 2; ++i)
#pragma unroll
    for (int j = 0; j < 2; ++j) acc[i][j] = (f32x4){0.f, 0.f, 0.f, 0.f};

  for (int pair = 0; pair < 2; ++pair) {
    const int K = pair ? K2 : K1;
    if (K == 0) continue;
    const float* A = pair ? A2 : A1;
    const float* W = pair ? W2 : W1;
    const float* arow = A + (size_t)(bm + sr) * K;
    const float* wrow = W + (size_t)(bn + sr) * K;
    for (int k0 = 0; k0 < K; k0 += 32) {
      __syncthreads();
      if (k0 + 32 <= K) {
        const float* pa = arow + k0 + sk;
        float4 a0 = *(const float4*)pa;
        float4 a1 = *(const float4*)(pa + 4);
        short* da = &sA[sr][sk];
        da[0] = f2bf(a0.x); da[1] = f2bf(a0.y); da[2] = f2bf(a0.z); da[3] = f2bf(a0.w);
        da[4] = f2bf(a1.x); da[5] = f2bf(a1.y); da[6] = f2bf(a1.z); da[7] = f2bf(a1.w);
        const float* pw = wrow + k0 + sk;
        float4 b0 = *(const float4*)pw;
        float4 b1 = *(const float4*)(pw + 4);
        short* db = &sB[sr][sk];
        db[0] = f2bf(b0.x); db[1] = f2bf(b0.y); db[2] = f2bf(b0.z); db[3] = f2bf(b0.w);
        db[4] = f2bf(b1.x); db[5] = f2bf(b1.y); db[6] = f2bf(b1.z); db[7] = f2bf(b1.w);
      } else {
        short* da = &sA[sr][sk];
        short* db = &sB[sr][sk];
#pragma unroll
        for (int j = 0; j < 8; ++j) {
          int k = k0 + sk + j;
          da[j] = (k < K) ? f2bf(arow[k]) : (short)0;
          db[j] = (k < K) ? f2bf(wrow[k]) : (short)0;
        }
      }
      __syncthreads();
      bf16x8 af[2], bfv[2];
      af[0]  = *(const bf16x8*)&sA[wr + l15][kq];
      af[1]  = *(const bf16x8*)&sA[wr + 16 + l15][kq];
      bfv[0] = *(const bf16x8*)&sB[wc + l15][kq];
      bfv[1] = *(const bf16x8*)&sB[wc + 16 + l15][kq];
#pragma unroll
      for (int i = 0; i < 2; ++i)
#pragma unroll
        for (int j = 0; j < 2; ++j)
          acc[i][j] = __builtin_amdgcn_mfma_f32_16x16x32_bf16(af[i], bfv[j], acc[i][j], 0, 0, 0);
    }
  }

#pragma unroll
  for (int i = 0; i < 2; ++i) {
#pragma unroll
    for (int j = 0; j < 2; ++j) {
      int n = bn + wc + j * 16 + l15;
      float bv = (bias1 ? bias1[n] : 0.f) + (bias2 ? bias2[n] : 0.f);
#pragma unroll
      for (int r = 0; r < 4; ++r) {
        int m = bm + wr + i * 16 + (lane >> 4) * 4 + r;
        float v = acc[i][j][r] + bv;
        if (act == 1) v = fmaxf(v, 0.f);
        out[(size_t)m * ldo + n] = v;
      }
    }
  }
}

// ---------------------------------------------------------------------------
// copy old context into GRU-input concat buffer [ctx | prenet_out]
// ---------------------------------------------------------------------------
__global__ __launch_bounds__(256) void copy_ctx_kernel(const float* __restrict__ ctx,
                                                       float* __restrict__ gruin)
{
  int idx = blockIdx.x * 256 + threadIdx.x;
  if (idx >= B_ * INP) return;
  int b = idx >> 9, j = idx & 511;
  gruin[(size_t)b * 768 + j] = ctx[idx];
}

// ---------------------------------------------------------------------------
// GRU cell elementwise
// ---------------------------------------------------------------------------
__global__ __launch_bounds__(256) void gru_cell_kernel(
    const float* __restrict__ gi, const float* __restrict__ gh,
    const float* __restrict__ h_old,
    float* __restrict__ h_out, float* __restrict__ ws_rnnin)
{
  int idx = blockIdx.x * 256 + threadIdx.x;
  if (idx >= B_ * DEC_) return;
  int b = idx >> 7, j = idx & 127;
  const float* gib = gi + (size_t)b * 384;
  const float* ghb = gh + (size_t)b * 384;
  float r = sigmoidf_(gib[j] + ghb[j]);
  float z = sigmoidf_(gib[128 + j] + ghb[128 + j]);
  float n = tanhf_(gib[256 + j] + r * ghb[256 + j]);
  float h = (1.f - z) * n + z * h_old[idx];
  h_out[idx] = h;
  ws_rnnin[(size_t)b * 640 + 512 + j] = h;
}

// ---------------------------------------------------------------------------
// Fused location-sensitive attention: conv31 + L-proj + tanh score + masked
// softmax + context. One block per batch row, 256 threads.
// ---------------------------------------------------------------------------
__global__ __launch_bounds__(256) void attn_kernel(
    const float* __restrict__ E,       // (B,T,512)
    const float* __restrict__ ESP,     // (B,T,128)
    const float* __restrict__ cum,     // (B,T)
    const int*   __restrict__ chars,   // (B,T)
    const float* __restrict__ convw,   // (32,31)
    const float* __restrict__ convb,   // (32,)
    const float* __restrict__ Lmat,    // (128,32)
    const float* __restrict__ Wq,      // (128,128)
    const float* __restrict__ Wqb,     // (128,)
    const float* __restrict__ vvec,    // (128,)
    const float* __restrict__ attn_new,// (B,128) new GRU hidden (d_out slot)
    float* __restrict__ out_scores,    // (B,T)
    float* __restrict__ out_cum,       // (B,T)
    float* __restrict__ out_ctx,       // (B,512)
    float* __restrict__ ws_ctx)        // rnn_in concat buffer, row stride 640
{
  __shared__ float s_cum[T_ + KS - 1];
  __shared__ float s_L[DEC_ * FILT];
  __shared__ float s_w[FILT * KS];
  __shared__ float s_cb[FILT];
  __shared__ float s_v[DEC_];
  __shared__ float s_ah[DEC_];
  __shared__ float s_pq[DEC_];
  __shared__ float s_u[T_];
  __shared__ float s_red[8];

  const int b = blockIdx.x;
  const int tid = threadIdx.x;

  for (int i = tid; i < T_ + KS - 1; i += 256) {
    int t = i - (KS / 2);
    s_cum[i] = (t >= 0 && t < T_) ? cum[(size_t)b * T_ + t] : 0.f;
  }
  for (int i = tid; i < DEC_ * FILT; i += 256) s_L[i] = Lmat[i];
  for (int i = tid; i < FILT * KS; i += 256) s_w[i] = convw[i];
  if (tid < FILT) s_cb[tid] = convb[tid];
  if (tid < DEC_) { s_v[tid] = vvec[tid]; s_ah[tid] = attn_new[(size_t)b * DEC_ + tid]; }
  __syncthreads();

  if (tid < DEC_) {
    float acc = Wqb[tid];
    const float* wrow = Wq + (size_t)tid * DEC_;
    for (int j = 0; j < DEC_; ++j) acc += wrow[j] * s_ah[j];
    s_pq[tid] = acc;
  }
  __syncthreads();

  // scores u[t]
  for (int t = tid; t < T_; t += 256) {
    float cf[FILT];
#pragma unroll
    for (int f = 0; f < FILT; ++f) {
      float a = s_cb[f];
      const float* wf = &s_w[f * KS];
#pragma unroll
      for (int k = 0; k < KS; ++k) a += s_cum[t + k] * wf[k];
      cf[f] = a;
    }
    const float4* esp4 = (const float4*)(ESP + ((size_t)b * T_ + t) * DEC_);
    float u = 0.f;
    for (int d4 = 0; d4 < DEC_ / 4; ++d4) {
      float4 e = esp4[d4];
      const float ev[4] = {e.x, e.y, e.z, e.w};
#pragma unroll
      for (int c = 0; c < 4; ++c) {
        int d = d4 * 4 + c;
        float pl = 0.f;
        const float* ld = &s_L[d * FILT];
#pragma unroll
        for (int f = 0; f < FILT; ++f) pl += cf[f] * ld[f];
        float x = s_pq[d] + ev[c] + pl;
        u += tanhf_(x) * s_v[d];
      }
    }
    if (chars[(size_t)b * T_ + t] == 0) u = 0.f;
    s_u[t] = u;
  }
  __syncthreads();

  // softmax over t
  float mx = -1e30f;
  for (int t = tid; t < T_; t += 256) mx = fmaxf(mx, s_u[t]);
#pragma unroll
  for (int o = 32; o >= 1; o >>= 1) mx = fmaxf(mx, __shfl_xor(mx, o));
  if ((tid & 63) == 0) s_red[tid >> 6] = mx;
  __syncthreads();
  mx = fmaxf(fmaxf(s_red[0], s_red[1]), fmaxf(s_red[2], s_red[3]));

  float sm = 0.f;
  for (int t = tid; t < T_; t += 256) {
    float e = __expf(s_u[t] - mx);
    s_u[t] = e;
    sm += e;
  }
#pragma unroll
  for (int o = 32; o >= 1; o >>= 1) sm += __shfl_xor(sm, o);
  if ((tid & 63) == 0) s_red[4 + (tid >> 6)] = sm;
  __syncthreads();
  sm = s_red[4] + s_red[5] + s_red[6] + s_red[7];
  float inv = 1.f / sm;
  for (int t = tid; t < T_; t += 256) {
    float s = s_u[t] * inv;
    s_u[t] = s;
    out_scores[(size_t)b * T_ + t] = s;
    out_cum[(size_t)b * T_ + t] = cum[(size_t)b * T_ + t] + s;
  }
  __syncthreads();

  // context: ctx[d] = sum_t s[t] * E[b,t,d]   (coalesced: lane = d)
  {
    float a0 = 0.f, a1 = 0.f;
    const float* Eb = E + (size_t)b * T_ * INP;
    for (int t = 0; t < T_; ++t) {
      float s = s_u[t];
      a0 += s * Eb[(size_t)t * INP + tid];
      a1 += s * Eb[(size_t)t * INP + 256 + tid];
    }
    out_ctx[(size_t)b * INP + tid] = a0;
    out_ctx[(size_t)b * INP + 256 + tid] = a1;
    ws_ctx[(size_t)b * 640 + tid] = a0;
    ws_ctx[(size_t)b * 640 + 256 + tid] = a1;
  }
}

// ---------------------------------------------------------------------------
// LSTM cell elementwise (+ residual x_out = x_in + h_new)
// ---------------------------------------------------------------------------
__global__ __launch_bounds__(256) void lstm_cell_kernel(
    const float* __restrict__ g, const float* __restrict__ c_old,
    const float* __restrict__ x_in,
    float* __restrict__ h_out, float* __restrict__ c_out,
    float* __restrict__ x_out)
{
  int idx = blockIdx.x * 256 + threadIdx.x;
  if (idx >= B_ * LSTM_) return;
  int b = idx >> 10, j = idx & 1023;
  const float* gb = g + (size_t)b * 4096;
  float ig = gb[j], fg = gb[1024 + j], gg = gb[2048 + j], og = gb[3072 + j];
  float cn = sigmoidf_(fg) * c_old[idx] + sigmoidf_(ig) * tanhf_(gg);
  float hn = sigmoidf_(og) * tanhf_(cn);
  h_out[idx] = hn;
  c_out[idx] = cn;
  x_out[idx] = x_in[idx] + hn;
}

// ---------------------------------------------------------------------------
// mel (80 rows of mel_w, stride MAXR) + stop head. One block per batch row.
// ---------------------------------------------------------------------------
__global__ __launch_bounds__(256) void mel_stop_kernel(
    const float* __restrict__ x3, const float* __restrict__ ctx,
    const float* __restrict__ mel_w, const float* __restrict__ stop_w,
    const float* __restrict__ stop_b,
    float* __restrict__ out_mels, float* __restrict__ out_stop)
{
  __shared__ float s_x[LSTM_];
  __shared__ float s_c[INP];
  __shared__ float s_red[4];
  int b = blockIdx.x, tid = threadIdx.x;
  for (int k = tid; k < LSTM_; k += 256) s_x[k] = x3[(size_t)b * LSTM_ + k];
  for (int k = tid; k < INP; k += 256) s_c[k] = ctx[(size_t)b * INP + k];
  __syncthreads();
  if (tid < NMELS) {
    const float* wrow = mel_w + (size_t)(tid * MAXR) * LSTM_;
    float a = 0.f;
    for (int k = 0; k < LSTM_; ++k) a += s_x[k] * wrow[k];
    out_mels[(size_t)b * NMELS + tid] = a;
  }
  float p = 0.f;
  for (int k = tid; k < LSTM_; k += 256) p += s_x[k] * stop_w[k];
  for (int k = tid; k < INP; k += 256) p += s_c[k] * stop_w[LSTM_ + k];
#pragma unroll
  for (int o = 32; o >= 1; o >>= 1) p += __shfl_xor(p, o);
  if ((tid & 63) == 0) s_red[tid >> 6] = p;
  __syncthreads();
  if (tid == 0) {
    float t = s_red[0] + s_red[1] + s_red[2] + s_red[3] + stop_b[0];
    out_stop[b] = sigmoidf_(t);
  }
}

// ---------------------------------------------------------------------------
extern "C" void kernel_launch(void* const* d_in, const int* in_sizes, int n_in,
                              void* d_out, int out_size, void* d_ws, size_t ws_size,
                              hipStream_t stream) {
  const float* enc   = (const float*)d_in[0];
  const float* esp   = (const float*)d_in[1];
  const float* prein = (const float*)d_in[2];
  const float* ah0   = (const float*)d_in[3];
  const float* h1_0  = (const float*)d_in[4];
  const float* h2_0  = (const float*)d_in[5];
  const float* c1_0  = (const float*)d_in[6];
  const float* c2_0  = (const float*)d_in[7];
  const float* ctx0  = (const float*)d_in[8];
  const float* cum   = (const float*)d_in[9];
  const int*   chars = (const int*)d_in[10];
  const float* pw1 = (const float*)d_in[11];
  const float* pb1 = (const float*)d_in[12];
  const float* pw2 = (const float*)d_in[13];
  const float* pb2 = (const float*)d_in[14];
  const float* gwih = (const float*)d_in[15];
  const float* gwhh = (const float*)d_in[16];
  const float* gbih = (const float*)d_in[17];
  const float* gbhh = (const float*)d_in[18];
  const float* cvw = (const float*)d_in[19];
  const float* cvb = (const float*)d_in[20];
  const float* lsaL = (const float*)d_in[21];
  const float* lsaW = (const float*)d_in[22];
  const float* lsaWb = (const float*)d_in[23];
  const float* lsav = (const float*)d_in[24];
  const float* riw = (const float*)d_in[25];
  const float* rib = (const float*)d_in[26];
  const float* l1wih = (const float*)d_in[27];
  const float* l1whh = (const float*)d_in[28];
  const float* l1bih = (const float*)d_in[29];
  const float* l1bhh = (const float*)d_in[30];
  const float* l2wih = (const float*)d_in[31];
  const float* l2whh = (const float*)d_in[32];
  const float* l2bih = (const float*)d_in[33];
  const float* l2bhh = (const float*)d_in[34];
  const float* melw = (const float*)d_in[35];
  const float* stopw = (const float*)d_in[36];
  const float* stopb = (const float*)d_in[37];

  float* out = (float*)d_out;
  float* o_mels   = out;             // (256,80,1)
  float* o_scores = out + 20480;     // (256,1,400)
  float* o_attn   = out + 122880;    // (256,128)
  float* o_h1     = out + 155648;    // (256,1024)
  float* o_h2     = out + 417792;
  float* o_c1     = out + 679936;
  float* o_c2     = out + 942080;
  float* o_ctx    = out + 1204224;   // (256,512)
  float* o_stop   = out + 1335296;   // (256,1)
  float* o_cum    = out + 1335552;   // (256,400)

  float* ws = (float*)d_ws;
  // region R (1,048,576 floats): early small buffers, later reused as LSTM gate buf
  float* ws_gruin = ws;                 // 256*768
  float* ws_h     = ws + 196608;        // 256*256
  float* ws_gi    = ws + 262144;        // 256*384
  float* ws_gh    = ws + 360448;        // 256*384
  float* ws_g     = ws;                 // 256*4096 (reuse of region R)
  float* ws_rnnin = ws + 1048576;       // 256*640
  float* ws_x     = ws + 1212416;       // 256*1024
  float* ws_x2    = ws + 1474560;       // 256*1024
  float* ws_x3    = ws + 1736704;       // 256*1024

  dim3 blk(256);

  // 1. gruin[:, :512] = old context
  copy_ctx_kernel<<<dim3(512), blk, 0, stream>>>(ctx0, ws_gruin);
  // 2. prenet layer 1: (256,80) -> (256,256), relu
  gemm_bf16<<<dim3(4, 4), blk, 0, stream>>>(prein, pw1, 80, nullptr, nullptr, 0,
                                            pb1, nullptr, ws_h, 256, 1);
  // 3. prenet layer 2 -> gruin[:, 512:768], relu
  gemm_bf16<<<dim3(4, 4), blk, 0, stream>>>(ws_h, pw2, 256, nullptr, nullptr, 0,
                                            pb2, nullptr, ws_gruin + 512, 768, 1);
  // 4. GRU gi = gruin @ w_ih^T + b_ih
  gemm_bf16<<<dim3(6, 4), blk, 0, stream>>>(ws_gruin, gwih, 768, nullptr, nullptr, 0,
                                            gbih, nullptr, ws_gi, 384, 0);
  // 5. GRU gh = h_old @ w_hh^T + b_hh
  gemm_bf16<<<dim3(6, 4), blk, 0, stream>>>(ah0, gwhh, 128, nullptr, nullptr, 0,
                                            gbhh, nullptr, ws_gh, 384, 0);
  // 6. GRU cell -> new attn_hidden (d_out) + rnn_in concat[:,512:640]
  gru_cell_kernel<<<dim3(128), blk, 0, stream>>>(ws_gi, ws_gh, ah0, o_attn, ws_rnnin);
  // 7. attention: scores, cumulative_new, context (d_out) + concat[:, :512]
  attn_kernel<<<dim3(256), blk, 0, stream>>>(enc, esp, cum, chars, cvw, cvb, lsaL,
                                             lsaW, lsaWb, lsav, o_attn,
                                             o_scores, o_cum, o_ctx, ws_rnnin);
  // 8. rnn_in: (256,640) -> (256,1024)
  gemm_bf16<<<dim3(16, 4), blk, 0, stream>>>(ws_rnnin, riw, 640, nullptr, nullptr, 0,
                                             rib, nullptr, ws_x, 1024, 0);
  // 9. LSTM1 gates: x@w_ih^T + h@w_hh^T + (b_ih+b_hh)
  gemm_bf16<<<dim3(64, 4), blk, 0, stream>>>(ws_x, l1wih, 1024, h1_0, l1whh, 1024,
                                             l1bih, l1bhh, ws_g, 4096, 0);
  // 10. LSTM1 cell -> h1, c1 (d_out); x2 = x + h1
  lstm_cell_kernel<<<dim3(1024), blk, 0, stream>>>(ws_g, c1_0, ws_x, o_h1, o_c1, ws_x2);
  // 11. LSTM2 gates
  gemm_bf16<<<dim3(64, 4), blk, 0, stream>>>(ws_x2, l2wih, 1024, h2_0, l2whh, 1024,
                                             l2bih, l2bhh, ws_g, 4096, 0);
  // 12. LSTM2 cell -> h2, c2 (d_out); x3 = x2 + h2
  lstm_cell_kernel<<<dim3(1024), blk, 0, stream>>>(ws_g, c2_0, ws_x2, o_h2, o_c2, ws_x3);
  // 13. mel + stop heads
  mel_stop_kernel<<<dim3(256), blk, 0, stream>>>(ws_x3, o_ctx, melw, stopw, stopb,
                                                 o_mels, o_stop);
}

// Round 2
// 376.078 us; speedup vs baseline: 1.2591x; 1.2591x over previous
//
#include <hip/hip_runtime.h>
#include <hip/hip_bf16.h>

#define B_ 256
#define T_ 400
#define NMELS 80
#define INP 512
#define DEC_ 128
#define LSTM_ 1024
#define PRE 256
#define FILT 32
#define KS 31
#define MAXR 20

typedef float f32x4 __attribute__((ext_vector_type(4)));
typedef short bf16x8 __attribute__((ext_vector_type(8)));

__device__ __forceinline__ short f2bf(float f) {
  union { float f; unsigned u; } v; v.f = f;
  unsigned u = v.u;
  unsigned r = (u + 0x7fffu + ((u >> 16) & 1u)) >> 16;
  return (short)r;
}

__device__ __forceinline__ bf16x8 pack8(float4 a0, float4 a1) {
  bf16x8 r;
  r[0] = f2bf(a0.x); r[1] = f2bf(a0.y); r[2] = f2bf(a0.z); r[3] = f2bf(a0.w);
  r[4] = f2bf(a1.x); r[5] = f2bf(a1.y); r[6] = f2bf(a1.z); r[7] = f2bf(a1.w);
  return r;
}

__device__ __forceinline__ float sigmoidf_(float x) {
  return 1.f / (1.f + __expf(-x));
}
__device__ __forceinline__ float tanhf_(float x) {
  float e = __expf(2.f * x);
  return 1.f - 2.f / (e + 1.f);
}

// ---------------------------------------------------------------------------
// Generic bf16-MFMA GEMM: out[m,n] = act( A1·W1^T + A2·W2^T + b1 + b2 )
// A: [M][K] f32 row-major, W: [N][K] f32 row-major. 64x64 tile, 4 waves.
// ---------------------------------------------------------------------------
__global__ __launch_bounds__(256) void gemm_bf16(
    const float* __restrict__ A1, const float* __restrict__ W1, int K1,
    const float* __restrict__ A2, const float* __restrict__ W2, int K2,
    const float* __restrict__ bias1, const float* __restrict__ bias2,
    float* __restrict__ out, int ldo, int act)
{
  __shared__ __align__(16) short sA[64][40];
  __shared__ __align__(16) short sB[64][40];
  const int tid  = threadIdx.x;
  const int lane = tid & 63;
  const int wave = tid >> 6;
  const int wr = (wave >> 1) * 32;
  const int wc = (wave & 1) * 32;
  const int bm = blockIdx.y * 64;
  const int bn = blockIdx.x * 64;
  const int sr = tid >> 2;         // 0..63
  const int sk = (tid & 3) * 8;    // 0,8,16,24
  const int l15 = lane & 15;
  const int kq  = (lane >> 4) * 8;

  f32x4 acc[2][2];
#pragma unroll
  for (int i = 0; i < 2; ++i)
#pragma unroll
    for (int j = 0; j < 2; ++j) acc[i][j] = (f32x4){0.f, 0.f, 0.f, 0.f};

  for (int pair = 0; pair < 2; ++pair) {
    const int K = pair ? K2 : K1;
    if (K == 0) continue;
    const float* A = pair ? A2 : A1;
    const float* W = pair ? W2 : W1;
    const float* arow = A + (size_t)(bm + sr) * K;
    const float* wrow = W + (size_t)(bn + sr) * K;
    for (int k0 = 0; k0 < K; k0 += 32) {
      __syncthreads();
      if (k0 + 32 <= K) {
        const float* pa = arow + k0 + sk;
        const float* pw = wrow + k0 + sk;
        *(bf16x8*)&sA[sr][sk] = pack8(*(const float4*)pa, *(const float4*)(pa + 4));
        *(bf16x8*)&sB[sr][sk] = pack8(*(const float4*)pw, *(const float4*)(pw + 4));
      } else {
        short* da = &sA[sr][sk];
        short* db = &sB[sr][sk];
#pragma unroll
        for (int j = 0; j < 8; ++j) {
          int k = k0 + sk + j;
          da[j] = (k < K) ? f2bf(arow[k]) : (short)0;
          db[j] = (k < K) ? f2bf(wrow[k]) : (short)0;
        }
      }
      __syncthreads();
      bf16x8 af[2], bfv[2];
      af[0]  = *(const bf16x8*)&sA[wr + l15][kq];
      af[1]  = *(const bf16x8*)&sA[wr + 16 + l15][kq];
      bfv[0] = *(const bf16x8*)&sB[wc + l15][kq];
      bfv[1] = *(const bf16x8*)&sB[wc + 16 + l15][kq];
#pragma unroll
      for (int i = 0; i < 2; ++i)
#pragma unroll
        for (int j = 0; j < 2; ++j)
          acc[i][j] = __builtin_amdgcn_mfma_f32_16x16x32_bf16(af[i], bfv[j], acc[i][j], 0, 0, 0);
    }
  }

#pragma unroll
  for (int i = 0; i < 2; ++i) {
#pragma unroll
    for (int j = 0; j < 2; ++j) {
      int n = bn + wc + j * 16 + l15;
      float bv = (bias1 ? bias1[n] : 0.f) + (bias2 ? bias2[n] : 0.f);
#pragma unroll
      for (int r = 0; r < 4; ++r) {
        int m = bm + wr + i * 16 + (lane >> 4) * 4 + r;
        float v = acc[i][j][r] + bv;
        if (act == 1) v = fmaxf(v, 0.f);
        out[(size_t)m * ldo + n] = v;
      }
    }
  }
}

// ---------------------------------------------------------------------------
__global__ __launch_bounds__(256) void copy_ctx_kernel(const float* __restrict__ ctx,
                                                       float* __restrict__ gruin)
{
  int idx = blockIdx.x * 256 + threadIdx.x;
  if (idx >= B_ * INP) return;
  int b = idx >> 9, j = idx & 511;
  gruin[(size_t)b * 768 + j] = ctx[idx];
}

// ---------------------------------------------------------------------------
__global__ __launch_bounds__(256) void gru_cell_kernel(
    const float* __restrict__ gi, const float* __restrict__ gh,
    const float* __restrict__ h_old,
    float* __restrict__ h_out, float* __restrict__ ws_rnnin)
{
  int idx = blockIdx.x * 256 + threadIdx.x;
  if (idx >= B_ * DEC_) return;
  int b = idx >> 7, j = idx & 127;
  const float* gib = gi + (size_t)b * 384;
  const float* ghb = gh + (size_t)b * 384;
  float r = sigmoidf_(gib[j] + ghb[j]);
  float z = sigmoidf_(gib[128 + j] + ghb[128 + j]);
  float n = tanhf_(gib[256 + j] + r * ghb[256 + j]);
  float h = (1.f - z) * n + z * h_old[idx];
  h_out[idx] = h;
  ws_rnnin[(size_t)b * 640 + 512 + j] = h;
}

// ---------------------------------------------------------------------------
// Attention scores: u[b,t] for one (b, half). Each thread owns one t.
// ---------------------------------------------------------------------------
__global__ __launch_bounds__(256) void attn_score_kernel(
    const float* __restrict__ ESP,     // (B,T,128)
    const float* __restrict__ cum,     // (B,T)
    const int*   __restrict__ chars,   // (B,T)
    const float* __restrict__ convw,   // (32,31)
    const float* __restrict__ convb,   // (32,)
    const float* __restrict__ Lmat,    // (128,32)
    const float* __restrict__ vvec,    // (128,)
    const float* __restrict__ pq,      // (B,128)
    float* __restrict__ out_u)         // (B,T)
{
  __shared__ float s_cum[200 + KS - 1];
  __shared__ float s_w[FILT * KS];
  __shared__ float s_cb[FILT];
  __shared__ float s_L[DEC_ * FILT];
  __shared__ float s_v[DEC_];
  __shared__ float s_pq[DEC_];

  const int half = blockIdx.x;      // 0..1
  const int b    = blockIdx.y;
  const int tid  = threadIdx.x;
  const int t0   = half * 200;

  for (int i = tid; i < 200 + KS - 1; i += 256) {
    int t = t0 - (KS / 2) + i;
    s_cum[i] = (t >= 0 && t < T_) ? cum[(size_t)b * T_ + t] : 0.f;
  }
  for (int i = tid; i < FILT * KS; i += 256) s_w[i] = convw[i];
  for (int i = tid; i < DEC_ * FILT; i += 256) s_L[i] = Lmat[i];
  if (tid < FILT) s_cb[tid] = convb[tid];
  if (tid < DEC_) { s_v[tid] = vvec[tid]; s_pq[tid] = pq[(size_t)b * DEC_ + tid]; }
  __syncthreads();

  if (tid >= 200) return;
  const int t = t0 + tid;

  float cf[FILT];
#pragma unroll
  for (int f = 0; f < FILT; ++f) {
    float a = s_cb[f];
    const float* wf = &s_w[f * KS];
#pragma unroll
    for (int k = 0; k < KS; ++k) a += s_cum[tid + k] * wf[k];
    cf[f] = a;
  }

  const float4* esp4 = (const float4*)(ESP + ((size_t)b * T_ + t) * DEC_);
  float u = 0.f;
  for (int d4 = 0; d4 < DEC_ / 4; ++d4) {
    float4 e = esp4[d4];
    const float ev[4] = {e.x, e.y, e.z, e.w};
#pragma unroll
    for (int c = 0; c < 4; ++c) {
      int d = d4 * 4 + c;
      float pl = 0.f;
      const float* ld = &s_L[d * FILT];
#pragma unroll
      for (int f = 0; f < FILT; ++f) pl += cf[f] * ld[f];
      float x = s_pq[d] + ev[c] + pl;
      u += tanhf_(x) * s_v[d];
    }
  }
  if (chars[(size_t)b * T_ + t] == 0) u = 0.f;
  out_u[(size_t)b * T_ + t] = u;
}

// ---------------------------------------------------------------------------
// Softmax over T per batch row; emits scores (d_out) and cumulative_new.
// ---------------------------------------------------------------------------
__global__ __launch_bounds__(256) void attn_softmax_kernel(
    const float* __restrict__ u_in, const float* __restrict__ cum,
    float* __restrict__ out_scores, float* __restrict__ out_cum)
{
  __shared__ float s_u[T_];
  __shared__ float s_red[8];
  const int b = blockIdx.x, tid = threadIdx.x;

  float mx = -1e30f;
  for (int t = tid; t < T_; t += 256) {
    float v = u_in[(size_t)b * T_ + t];
    s_u[t] = v;
    mx = fmaxf(mx, v);
  }
#pragma unroll
  for (int o = 32; o >= 1; o >>= 1) mx = fmaxf(mx, __shfl_xor(mx, o));
  if ((tid & 63) == 0) s_red[tid >> 6] = mx;
  __syncthreads();
  mx = fmaxf(fmaxf(s_red[0], s_red[1]), fmaxf(s_red[2], s_red[3]));

  float sm = 0.f;
  for (int t = tid; t < T_; t += 256) {
    float e = __expf(s_u[t] - mx);
    s_u[t] = e;
    sm += e;
  }
#pragma unroll
  for (int o = 32; o >= 1; o >>= 1) sm += __shfl_xor(sm, o);
  if ((tid & 63) == 0) s_red[4 + (tid >> 6)] = sm;
  __syncthreads();
  sm = s_red[4] + s_red[5] + s_red[6] + s_red[7];
  float inv = 1.f / sm;
  for (int t = tid; t < T_; t += 256) {
    float s = s_u[t] * inv;
    out_scores[(size_t)b * T_ + t] = s;
    out_cum[(size_t)b * T_ + t] = cum[(size_t)b * T_ + t] + s;
  }
}

// ---------------------------------------------------------------------------
// Context partials: block (tc, dh, b) handles 100 t-steps x 256 d-cols.
// ---------------------------------------------------------------------------
#define TCH 4
__global__ __launch_bounds__(256) void ctx_part_kernel(
    const float* __restrict__ E,        // (B,T,512)
    const float* __restrict__ scores,   // (B,T)
    float* __restrict__ part)           // (TCH,B,512)
{
  const int tc = blockIdx.x >> 1;
  const int dh = blockIdx.x & 1;
  const int b  = blockIdx.y;
  const int d  = dh * 256 + threadIdx.x;
  const float* Eb = E + (size_t)b * T_ * INP + d;
  const float* sb = scores + (size_t)b * T_ + tc * (T_ / TCH);
  float acc = 0.f;
#pragma unroll 4
  for (int t = 0; t < T_ / TCH; ++t)
    acc += sb[t] * Eb[(size_t)(tc * (T_ / TCH) + t) * INP];
  part[((size_t)tc * B_ + b) * INP + d] = acc;
}

__global__ __launch_bounds__(256) void ctx_reduce_kernel(
    const float* __restrict__ part,
    float* __restrict__ out_ctx, float* __restrict__ ws_rnnin)
{
  int idx = blockIdx.x * 256 + threadIdx.x;
  if (idx >= B_ * INP) return;
  int b = idx >> 9, d = idx & 511;
  float a = 0.f;
#pragma unroll
  for (int tc = 0; tc < TCH; ++tc) a += part[((size_t)tc * B_ + b) * INP + d];
  out_ctx[idx] = a;
  ws_rnnin[(size_t)b * 640 + d] = a;
}

// ---------------------------------------------------------------------------
__global__ __launch_bounds__(256) void lstm_cell_kernel(
    const float* __restrict__ g, const float* __restrict__ c_old,
    const float* __restrict__ x_in,
    float* __restrict__ h_out, float* __restrict__ c_out,
    float* __restrict__ x_out)
{
  int idx = blockIdx.x * 256 + threadIdx.x;
  if (idx >= B_ * LSTM_) return;
  int b = idx >> 10, j = idx & 1023;
  const float* gb = g + (size_t)b * 4096;
  float ig = gb[j], fg = gb[1024 + j], gg = gb[2048 + j], og = gb[3072 + j];
  float cn = sigmoidf_(fg) * c_old[idx] + sigmoidf_(ig) * tanhf_(gg);
  float hn = sigmoidf_(og) * tanhf_(cn);
  h_out[idx] = hn;
  c_out[idx] = cn;
  x_out[idx] = x_in[idx] + hn;
}

// ---------------------------------------------------------------------------
__global__ __launch_bounds__(256) void mel_stop_kernel(
    const float* __restrict__ x3, const float* __restrict__ ctx,
    const float* __restrict__ mel_w, const float* __restrict__ stop_w,
    const float* __restrict__ stop_b,
    float* __restrict__ out_mels, float* __restrict__ out_stop)
{
  __shared__ float s_x[LSTM_];
  __shared__ float s_c[INP];
  __shared__ float s_red[4];
  int b = blockIdx.x, tid = threadIdx.x;
  for (int k = tid; k < LSTM_; k += 256) s_x[k] = x3[(size_t)b * LSTM_ + k];
  for (int k = tid; k < INP; k += 256) s_c[k] = ctx[(size_t)b * INP + k];
  __syncthreads();
  if (tid < NMELS) {
    const float* wrow = mel_w + (size_t)(tid * MAXR) * LSTM_;
    float a = 0.f;
    for (int k = 0; k < LSTM_; ++k) a += s_x[k] * wrow[k];
    out_mels[(size_t)b * NMELS + tid] = a;
  }
  float p = 0.f;
  for (int k = tid; k < LSTM_; k += 256) p += s_x[k] * stop_w[k];
  for (int k = tid; k < INP; k += 256) p += s_c[k] * stop_w[LSTM_ + k];
#pragma unroll
  for (int o = 32; o >= 1; o >>= 1) p += __shfl_xor(p, o);
  if ((tid & 63) == 0) s_red[tid >> 6] = p;
  __syncthreads();
  if (tid == 0) {
    float t = s_red[0] + s_red[1] + s_red[2] + s_red[3] + stop_b[0];
    out_stop[b] = sigmoidf_(t);
  }
}

// ---------------------------------------------------------------------------
extern "C" void kernel_launch(void* const* d_in, const int* in_sizes, int n_in,
                              void* d_out, int out_size, void* d_ws, size_t ws_size,
                              hipStream_t stream) {
  const float* enc   = (const float*)d_in[0];
  const float* esp   = (const float*)d_in[1];
  const float* prein = (const float*)d_in[2];
  const float* ah0   = (const float*)d_in[3];
  const float* h1_0  = (const float*)d_in[4];
  const float* h2_0  = (const float*)d_in[5];
  const float* c1_0  = (const float*)d_in[6];
  const float* c2_0  = (const float*)d_in[7];
  const float* ctx0  = (const float*)d_in[8];
  const float* cum   = (const float*)d_in[9];
  const int*   chars = (const int*)d_in[10];
  const float* pw1 = (const float*)d_in[11];
  const float* pb1 = (const float*)d_in[12];
  const float* pw2 = (const float*)d_in[13];
  const float* pb2 = (const float*)d_in[14];
  const float* gwih = (const float*)d_in[15];
  const float* gwhh = (const float*)d_in[16];
  const float* gbih = (const float*)d_in[17];
  const float* gbhh = (const float*)d_in[18];
  const float* cvw = (const float*)d_in[19];
  const float* cvb = (const float*)d_in[20];
  const float* lsaL = (const float*)d_in[21];
  const float* lsaW = (const float*)d_in[22];
  const float* lsaWb = (const float*)d_in[23];
  const float* lsav = (const float*)d_in[24];
  const float* riw = (const float*)d_in[25];
  const float* rib = (const float*)d_in[26];
  const float* l1wih = (const float*)d_in[27];
  const float* l1whh = (const float*)d_in[28];
  const float* l1bih = (const float*)d_in[29];
  const float* l1bhh = (const float*)d_in[30];
  const float* l2wih = (const float*)d_in[31];
  const float* l2whh = (const float*)d_in[32];
  const float* l2bih = (const float*)d_in[33];
  const float* l2bhh = (const float*)d_in[34];
  const float* melw = (const float*)d_in[35];
  const float* stopw = (const float*)d_in[36];
  const float* stopb = (const float*)d_in[37];

  float* out = (float*)d_out;
  float* o_mels   = out;             // (256,80,1)
  float* o_scores = out + 20480;     // (256,1,400)
  float* o_attn   = out + 122880;    // (256,128)
  float* o_h1     = out + 155648;    // (256,1024)
  float* o_h2     = out + 417792;
  float* o_c1     = out + 679936;
  float* o_c2     = out + 942080;
  float* o_ctx    = out + 1204224;   // (256,512)
  float* o_stop   = out + 1335296;   // (256,1)
  float* o_cum    = out + 1335552;   // (256,400)

  float* ws = (float*)d_ws;
  // Region R [0, 1048576): time-shared.
  //   phase 1 (prenet/GRU): gruin, h, gi, gh
  //   phase 2 (attention): u, pq, ctx partials
  //   phase 3 (LSTM): gate buffer g
  float* ws_gruin = ws;                 // 256*768
  float* ws_h     = ws + 196608;        // 256*256
  float* ws_gi    = ws + 262144;        // 256*384
  float* ws_gh    = ws + 360448;        // 256*384
  float* ws_u     = ws;                 // 256*400 (phase 2)
  float* ws_pq    = ws + 102400;        // 256*128
  float* ws_part  = ws + 135168;        // 4*256*512
  float* ws_g     = ws;                 // 256*4096 (phase 3)
  float* ws_rnnin = ws + 1048576;       // 256*640
  float* ws_x     = ws + 1212416;       // 256*1024
  float* ws_x2    = ws + 1474560;       // 256*1024
  float* ws_x3    = ws + 1736704;       // 256*1024

  dim3 blk(256);

  // 1. gruin[:, :512] = old context
  copy_ctx_kernel<<<dim3(512), blk, 0, stream>>>(ctx0, ws_gruin);
  // 2-3. prenet
  gemm_bf16<<<dim3(4, 4), blk, 0, stream>>>(prein, pw1, 80, nullptr, nullptr, 0,
                                            pb1, nullptr, ws_h, 256, 1);
  gemm_bf16<<<dim3(4, 4), blk, 0, stream>>>(ws_h, pw2, 256, nullptr, nullptr, 0,
                                            pb2, nullptr, ws_gruin + 512, 768, 1);
  // 4-6. GRU
  gemm_bf16<<<dim3(6, 4), blk, 0, stream>>>(ws_gruin, gwih, 768, nullptr, nullptr, 0,
                                            gbih, nullptr, ws_gi, 384, 0);
  gemm_bf16<<<dim3(6, 4), blk, 0, stream>>>(ah0, gwhh, 128, nullptr, nullptr, 0,
                                            gbhh, nullptr, ws_gh, 384, 0);
  gru_cell_kernel<<<dim3(128), blk, 0, stream>>>(ws_gi, ws_gh, ah0, o_attn, ws_rnnin);
  // 7. processed_query = attn_hidden @ W^T + b
  gemm_bf16<<<dim3(2, 4), blk, 0, stream>>>(o_attn, lsaW, 128, nullptr, nullptr, 0,
                                            lsaWb, nullptr, ws_pq, 128, 0);
  // 8. scores u
  attn_score_kernel<<<dim3(2, B_), blk, 0, stream>>>(esp, cum, chars, cvw, cvb,
                                                     lsaL, lsav, ws_pq, ws_u);
  // 9. softmax -> scores, cumulative_new
  attn_softmax_kernel<<<dim3(B_), blk, 0, stream>>>(ws_u, cum, o_scores, o_cum);
  // 10-11. context
  ctx_part_kernel<<<dim3(2 * TCH, B_), blk, 0, stream>>>(enc, o_scores, ws_part);
  ctx_reduce_kernel<<<dim3(512), blk, 0, stream>>>(ws_part, o_ctx, ws_rnnin);
  // 12. rnn_in
  gemm_bf16<<<dim3(16, 4), blk, 0, stream>>>(ws_rnnin, riw, 640, nullptr, nullptr, 0,
                                             rib, nullptr, ws_x, 1024, 0);
  // 13-14. LSTM1
  gemm_bf16<<<dim3(64, 4), blk, 0, stream>>>(ws_x, l1wih, 1024, h1_0, l1whh, 1024,
                                             l1bih, l1bhh, ws_g, 4096, 0);
  lstm_cell_kernel<<<dim3(1024), blk, 0, stream>>>(ws_g, c1_0, ws_x, o_h1, o_c1, ws_x2);
  // 15-16. LSTM2
  gemm_bf16<<<dim3(64, 4), blk, 0, stream>>>(ws_x2, l2wih, 1024, h2_0, l2whh, 1024,
                                             l2bih, l2bhh, ws_g, 4096, 0);
  lstm_cell_kernel<<<dim3(1024), blk, 0, stream>>>(ws_g, c2_0, ws_x2, o_h2, o_c2, ws_x3);
  // 17. heads
  mel_stop_kernel<<<dim3(256), blk, 0, stream>>>(ws_x3, o_ctx, melw, stopw, stopb,
                                                 o_mels, o_stop);
}

// Round 3
// 357.499 us; speedup vs baseline: 1.3245x; 1.0520x over previous
//
#include <hip/hip_runtime.h>
#include <hip/hip_bf16.h>

#define B_ 256
#define T_ 400
#define NMELS 80
#define INP 512
#define DEC_ 128
#define LSTM_ 1024
#define FILT 32
#define KS 31
#define MAXR 20

typedef float f32x4 __attribute__((ext_vector_type(4)));
typedef short bf16x8 __attribute__((ext_vector_type(8)));

__device__ __forceinline__ short f2bf(float f) {
  union { float f; unsigned u; } v; v.f = f;
  unsigned u = v.u;
  unsigned r = (u + 0x7fffu + ((u >> 16) & 1u)) >> 16;
  return (short)r;
}

__device__ __forceinline__ bf16x8 pack8(float4 a0, float4 a1) {
  bf16x8 r;
  r[0] = f2bf(a0.x); r[1] = f2bf(a0.y); r[2] = f2bf(a0.z); r[3] = f2bf(a0.w);
  r[4] = f2bf(a1.x); r[5] = f2bf(a1.y); r[6] = f2bf(a1.z); r[7] = f2bf(a1.w);
  return r;
}

__device__ __forceinline__ float sigmoidf_(float x) {
  return 1.f / (1.f + __expf(-x));
}
__device__ __forceinline__ float tanhf_(float x) {
  float e = __expf(2.f * x);
  return 1.f - 2.f / (e + 1.f);
}

// ---------------------------------------------------------------------------
// Generic bf16-MFMA GEMM, dual operand pairs, reg-double-buffered staging.
// out[m,n] = act( A1·W1^T + A2·W2^T + b1 + b2 )   (A,W row-major, ld params)
// zmode: 0 = single dispatch (both pairs, bias added)
//        1 = grid.z = pair index (partials, no bias)
//        2 = grid.z = pair*2 + K-half (partials, no bias)
// For zmode>0 each z writes its partial at out + z*M*ldo.
// ---------------------------------------------------------------------------
__global__ __launch_bounds__(256) void gemm_bf16(
    const float* __restrict__ A1, int lda1, const float* __restrict__ W1, int ldw1, int K1,
    const float* __restrict__ A2, int lda2, const float* __restrict__ W2, int ldw2, int K2,
    const float* __restrict__ bias1, const float* __restrict__ bias2,
    float* __restrict__ out, int ldo, int act, int zmode)
{
  __shared__ __align__(16) short sA[64][40];
  __shared__ __align__(16) short sB[64][40];
  const int tid  = threadIdx.x;
  const int lane = tid & 63;
  const int wave = tid >> 6;
  const int wr = (wave >> 1) * 32;
  const int wc = (wave & 1) * 32;
  const int bm = blockIdx.y * 64;
  const int bn = blockIdx.x * 64;
  const int sr = tid >> 2;         // 0..63
  const int sk = (tid & 3) * 8;    // 0,8,16,24
  const int l15 = lane & 15;
  const int kq  = (lane >> 4) * 8;

  int kb1 = 0, ke1 = K1, kb2 = 0, ke2 = K2;
  if (zmode == 1) {
    if (blockIdx.z == 0) ke2 = 0; else ke1 = 0;
  } else if (zmode == 2) {
    int p = blockIdx.z >> 1, h = blockIdx.z & 1;
    if (p == 0) { ke2 = 0; int half = K1 >> 1; kb1 = h * half; ke1 = kb1 + half; }
    else        { ke1 = 0; int half = K2 >> 1; kb2 = h * half; ke2 = kb2 + half; }
  }
  float* outp = out;
  if (zmode > 0) outp += (size_t)blockIdx.z * (size_t)(gridDim.y * 64) * ldo;

  f32x4 acc[2][2];
#pragma unroll
  for (int i = 0; i < 2; ++i)
#pragma unroll
    for (int j = 0; j < 2; ++j) acc[i][j] = (f32x4){0.f, 0.f, 0.f, 0.f};

  for (int pair = 0; pair < 2; ++pair) {
    const int kb = pair ? kb2 : kb1;
    const int ke = pair ? ke2 : ke1;
    if (ke <= kb) continue;
    const float* A = pair ? A2 : A1;
    const float* W = pair ? W2 : W1;
    const int lda = pair ? lda2 : lda1;
    const int ldw = pair ? ldw2 : ldw1;
    const float* arow = A + (size_t)(bm + sr) * lda;
    const float* wrow = W + (size_t)(bn + sr) * ldw;

    float4 ra0, ra1, rb0, rb1;
    if (kb + 32 <= ke) {
      const float* pa = arow + kb + sk;
      const float* pw = wrow + kb + sk;
      ra0 = *(const float4*)pa; ra1 = *(const float4*)(pa + 4);
      rb0 = *(const float4*)pw; rb1 = *(const float4*)(pw + 4);
    }
    for (int k0 = kb; k0 < ke; k0 += 32) {
      __syncthreads();
      if (k0 + 32 <= ke) {
        *(bf16x8*)&sA[sr][sk] = pack8(ra0, ra1);
        *(bf16x8*)&sB[sr][sk] = pack8(rb0, rb1);
        if (k0 + 64 <= ke) {          // prefetch next step
          const float* pa = arow + k0 + 32 + sk;
          const float* pw = wrow + k0 + 32 + sk;
          ra0 = *(const float4*)pa; ra1 = *(const float4*)(pa + 4);
          rb0 = *(const float4*)pw; rb1 = *(const float4*)(pw + 4);
        }
      } else {                        // K tail (prenet1 only)
        short* da = &sA[sr][sk];
        short* db = &sB[sr][sk];
#pragma unroll
        for (int j = 0; j < 8; ++j) {
          int k = k0 + sk + j;
          da[j] = (k < ke) ? f2bf(arow[k]) : (short)0;
          db[j] = (k < ke) ? f2bf(wrow[k]) : (short)0;
        }
      }
      __syncthreads();
      bf16x8 af[2], bfv[2];
      af[0]  = *(const bf16x8*)&sA[wr + l15][kq];
      af[1]  = *(const bf16x8*)&sA[wr + 16 + l15][kq];
      bfv[0] = *(const bf16x8*)&sB[wc + l15][kq];
      bfv[1] = *(const bf16x8*)&sB[wc + 16 + l15][kq];
#pragma unroll
      for (int i = 0; i < 2; ++i)
#pragma unroll
        for (int j = 0; j < 2; ++j)
          acc[i][j] = __builtin_amdgcn_mfma_f32_16x16x32_bf16(af[i], bfv[j], acc[i][j], 0, 0, 0);
    }
  }

#pragma unroll
  for (int i = 0; i < 2; ++i) {
#pragma unroll
    for (int j = 0; j < 2; ++j) {
      int n = bn + wc + j * 16 + l15;
      float bv = 0.f;
      if (zmode == 0) bv = (bias1 ? bias1[n] : 0.f) + (bias2 ? bias2[n] : 0.f);
#pragma unroll
      for (int r = 0; r < 4; ++r) {
        int m = bm + wr + i * 16 + (lane >> 4) * 4 + r;
        float v = acc[i][j][r] + bv;
        if (act == 1) v = fmaxf(v, 0.f);
        outp[(size_t)m * ldo + n] = v;
      }
    }
  }
}

// ---------------------------------------------------------------------------
// Fused GRU tail: gh GEMV + GRU cell + processed_query GEMV. One block per b.
// gi_part: [2][B][384] partials (no bias).
// ---------------------------------------------------------------------------
#define GI_SEG (256 * 384)
__global__ __launch_bounds__(256) void gru_fused_kernel(
    const float* __restrict__ gi_part,
    const float* __restrict__ whh, const float* __restrict__ bih,
    const float* __restrict__ bhh, const float* __restrict__ h_old,
    const float* __restrict__ Wq, const float* __restrict__ Wqb,
    float* __restrict__ h_out, float* __restrict__ pq_out)
{
  __shared__ float s_h[DEC_];
  __shared__ float s_gh[3 * DEC_];
  __shared__ float s_h2[DEC_];
  const int b = blockIdx.x, tid = threadIdx.x;
  if (tid < DEC_) s_h[tid] = h_old[(size_t)b * DEC_ + tid];
  __syncthreads();
  for (int n = tid; n < 3 * DEC_; n += 256) {
    const float4* wr4 = (const float4*)(whh + (size_t)n * DEC_);
    float ax = 0.f, ay = 0.f, az = 0.f, aw = 0.f;
#pragma unroll
    for (int q = 0; q < DEC_ / 4; ++q) {
      float4 w = wr4[q];
      ax += w.x * s_h[q * 4];
      ay += w.y * s_h[q * 4 + 1];
      az += w.z * s_h[q * 4 + 2];
      aw += w.w * s_h[q * 4 + 3];
    }
    s_gh[n] = bhh[n] + ax + ay + az + aw;
  }
  __syncthreads();
  if (tid < DEC_) {
    size_t base = (size_t)b * 384;
    float gir = gi_part[base + tid]       + gi_part[GI_SEG + base + tid]       + bih[tid];
    float giz = gi_part[base + 128 + tid] + gi_part[GI_SEG + base + 128 + tid] + bih[128 + tid];
    float gin = gi_part[base + 256 + tid] + gi_part[GI_SEG + base + 256 + tid] + bih[256 + tid];
    float r = sigmoidf_(gir + s_gh[tid]);
    float z = sigmoidf_(giz + s_gh[128 + tid]);
    float n = tanhf_(gin + r * s_gh[256 + tid]);
    float h = (1.f - z) * n + z * s_h[tid];
    s_h2[tid] = h;
    h_out[(size_t)b * DEC_ + tid] = h;
  }
  __syncthreads();
  if (tid < DEC_) {
    const float4* wr4 = (const float4*)(Wq + (size_t)tid * DEC_);
    float ax = 0.f, ay = 0.f, az = 0.f, aw = 0.f;
#pragma unroll
    for (int q = 0; q < DEC_ / 4; ++q) {
      float4 w = wr4[q];
      ax += w.x * s_h2[q * 4];
      ay += w.y * s_h2[q * 4 + 1];
      az += w.z * s_h2[q * 4 + 2];
      aw += w.w * s_h2[q * 4 + 3];
    }
    pq_out[(size_t)b * DEC_ + tid] = Wqb[tid] + ax + ay + az + aw;
  }
}

// ---------------------------------------------------------------------------
// Attention scores via MFMA. Block (half, b): 200 t's. conv31 -> bf16 LDS,
// PL = conv @ L^T via 13x8 MFMA tiles, epilogue tanh + v-dot + mask.
// ---------------------------------------------------------------------------
__global__ __launch_bounds__(256) void attn_score_kernel(
    const float* __restrict__ ESP,     // (B,T,128)
    const float* __restrict__ cum,     // (B,T)
    const int*   __restrict__ chars,   // (B,T)
    const float* __restrict__ convw,   // (32,31)
    const float* __restrict__ convb,   // (32,)
    const float* __restrict__ Lmat,    // (128,32)
    const float* __restrict__ vvec,    // (128,)
    const float* __restrict__ pq,      // (B,128)
    float* __restrict__ out_u)         // (B,T)
{
  __shared__ float s_cum[232];
  __shared__ __align__(16) short s_conv[208][40];
  __shared__ __align__(16) short s_L[128][40];
  __shared__ float s_w[FILT * KS];
  __shared__ float s_cb[FILT];
  __shared__ float s_pq[DEC_];
  __shared__ float s_v[DEC_];

  const int half = blockIdx.x;
  const int b    = blockIdx.y;
  const int tid  = threadIdx.x;
  const int t0   = half * 200;

  for (int i = tid; i < 230; i += 256) {
    int t = t0 - 15 + i;
    s_cum[i] = (t >= 0 && t < T_) ? cum[(size_t)b * T_ + t] : 0.f;
  }
  for (int i = tid; i < FILT * KS; i += 256) s_w[i] = convw[i];
  for (int i = tid; i < DEC_ * FILT; i += 256) s_L[i >> 5][i & 31] = f2bf(Lmat[i]);
  if (tid < FILT) s_cb[tid] = convb[tid];
  if (tid < DEC_) { s_pq[tid] = pq[(size_t)b * DEC_ + tid]; s_v[tid] = vvec[tid]; }
  // zero pad rows 200..207 of conv tile
  s_conv[200 + (tid >> 5)][tid & 31] = 0;
  __syncthreads();

  if (tid < 200) {
    float c[KS];
#pragma unroll
    for (int k = 0; k < KS; ++k) c[k] = s_cum[tid + k];
#pragma unroll
    for (int f = 0; f < FILT; ++f) {
      float a = s_cb[f];
#pragma unroll
      for (int k = 0; k < KS; ++k) a += c[k] * s_w[f * KS + k];
      s_conv[tid][f] = f2bf(a);
    }
  }
  __syncthreads();

  const int lane = tid & 63, wave = tid >> 6;
  const int l15 = lane & 15, kq = (lane >> 4) * 8;
  for (int m = wave; m < 13; m += 4) {
    bf16x8 af = *(const bf16x8*)&s_conv[m * 16 + l15][kq];
    f32x4 acc[8];
#pragma unroll
    for (int n = 0; n < 8; ++n) {
      bf16x8 bf = *(const bf16x8*)&s_L[n * 16 + l15][kq];
      acc[n] = __builtin_amdgcn_mfma_f32_16x16x32_bf16(af, bf, (f32x4){0.f,0.f,0.f,0.f}, 0, 0, 0);
    }
    const int trow = m * 16 + (lane >> 4) * 4;
    float u[4] = {0.f, 0.f, 0.f, 0.f};
#pragma unroll
    for (int n = 0; n < 8; ++n) {
      int d = n * 16 + l15;
      float pqd = s_pq[d], vd = s_v[d];
#pragma unroll
      for (int r = 0; r < 4; ++r) {
        int tl = trow + r;
        if (tl < 200) {
          float x = acc[n][r] + pqd + ESP[((size_t)b * T_ + t0 + tl) * DEC_ + d];
          u[r] += tanhf_(x) * vd;
        }
      }
    }
#pragma unroll
    for (int r = 0; r < 4; ++r) {
#pragma unroll
      for (int o = 1; o < 16; o <<= 1) u[r] += __shfl_xor(u[r], o);
    }
    if (l15 == 0) {
#pragma unroll
      for (int r = 0; r < 4; ++r) {
        int tl = trow + r;
        if (tl < 200) {
          int t = t0 + tl;
          float uu = u[r];
          if (chars[(size_t)b * T_ + t] == 0) uu = 0.f;
          out_u[(size_t)b * T_ + t] = uu;
        }
      }
    }
  }
}

// ---------------------------------------------------------------------------
// Softmax (redundant per tc-block) + context partial. Block (tc, b).
// tc==0 block also writes scores + cumulative_new.
// ---------------------------------------------------------------------------
#define TCH 4
__global__ __launch_bounds__(256) void ctx_smax_part_kernel(
    const float* __restrict__ E,        // (B,T,512)
    const float* __restrict__ u_in,     // (B,T)
    const float* __restrict__ cum,      // (B,T)
    float* __restrict__ out_scores, float* __restrict__ out_cum,
    float* __restrict__ part)           // (TCH,B,512)
{
  __shared__ float s_u[T_];
  __shared__ float s_red[8];
  const int tc = blockIdx.x, b = blockIdx.y, tid = threadIdx.x;
  const int lane = tid & 63, wave = tid >> 6;

  float mx = -1e30f;
  for (int t = tid; t < T_; t += 256) {
    float v = u_in[(size_t)b * T_ + t];
    s_u[t] = v;
    mx = fmaxf(mx, v);
  }
#pragma unroll
  for (int o = 32; o >= 1; o >>= 1) mx = fmaxf(mx, __shfl_xor(mx, o));
  if (lane == 0) s_red[wave] = mx;
  __syncthreads();
  mx = fmaxf(fmaxf(s_red[0], s_red[1]), fmaxf(s_red[2], s_red[3]));

  float sm = 0.f;
  for (int t = tid; t < T_; t += 256) {
    float e = __expf(s_u[t] - mx);
    s_u[t] = e;
    sm += e;
  }
#pragma unroll
  for (int o = 32; o >= 1; o >>= 1) sm += __shfl_xor(sm, o);
  if (lane == 0) s_red[4 + wave] = sm;
  __syncthreads();
  sm = s_red[4] + s_red[5] + s_red[6] + s_red[7];
  float inv = 1.f / sm;
  for (int t = tid; t < T_; t += 256) {
    float s = s_u[t] * inv;
    s_u[t] = s;
    if (tc == 0) {
      out_scores[(size_t)b * T_ + t] = s;
      out_cum[(size_t)b * T_ + t] = cum[(size_t)b * T_ + t] + s;
    }
  }
  __syncthreads();

  // context partial for 100 t's, thread owns float2 of d
  const float2* Eb = (const float2*)(E + (size_t)b * T_ * INP + (size_t)tc * 100 * INP) + tid;
  const float* su = &s_u[tc * 100];
  float2 a0 = {0.f, 0.f}, a1 = {0.f, 0.f}, a2 = {0.f, 0.f}, a3 = {0.f, 0.f};
  for (int t = 0; t < 100; t += 4) {
    float s0 = su[t], s1 = su[t + 1], s2 = su[t + 2], s3 = su[t + 3];
    float2 e0 = Eb[(size_t)(t)     * 256];
    float2 e1 = Eb[(size_t)(t + 1) * 256];
    float2 e2 = Eb[(size_t)(t + 2) * 256];
    float2 e3 = Eb[(size_t)(t + 3) * 256];
    a0.x += s0 * e0.x; a0.y += s0 * e0.y;
    a1.x += s1 * e1.x; a1.y += s1 * e1.y;
    a2.x += s2 * e2.x; a2.y += s2 * e2.y;
    a3.x += s3 * e3.x; a3.y += s3 * e3.y;
  }
  float2 r;
  r.x = (a0.x + a1.x) + (a2.x + a3.x);
  r.y = (a0.y + a1.y) + (a2.y + a3.y);
  *(float2*)&part[((size_t)tc * B_ + b) * INP + 2 * tid] = r;
}

__global__ __launch_bounds__(256) void ctx_reduce_kernel(
    const float* __restrict__ part, float* __restrict__ out_ctx)
{
  int idx = blockIdx.x * 256 + threadIdx.x;
  if (idx >= B_ * INP) return;
  int b = idx >> 9, d = idx & 511;
  float a = 0.f;
#pragma unroll
  for (int tc = 0; tc < TCH; ++tc) a += part[((size_t)tc * B_ + b) * INP + d];
  out_ctx[idx] = a;
}

// ---------------------------------------------------------------------------
// LSTM cell: sum 4 gate partials + biases, cell math, residual.
// ---------------------------------------------------------------------------
__global__ __launch_bounds__(256) void lstm_cell_kernel(
    const float* __restrict__ g4, const float* __restrict__ bih,
    const float* __restrict__ bhh, const float* __restrict__ c_old,
    const float* __restrict__ x_in,
    float* __restrict__ h_out, float* __restrict__ c_out,
    float* __restrict__ x_out)
{
  const size_t SEG = (size_t)B_ * 4096;
  int idx = blockIdx.x * 256 + threadIdx.x;
  if (idx >= B_ * LSTM_) return;
  int b = idx >> 10, j = idx & 1023;
  const float* gb = g4 + (size_t)b * 4096;
  float ig = gb[j]        + gb[SEG + j]        + gb[2*SEG + j]        + gb[3*SEG + j]        + bih[j]        + bhh[j];
  float fg = gb[1024 + j] + gb[SEG + 1024 + j] + gb[2*SEG + 1024 + j] + gb[3*SEG + 1024 + j] + bih[1024 + j] + bhh[1024 + j];
  float gg = gb[2048 + j] + gb[SEG + 2048 + j] + gb[2*SEG + 2048 + j] + gb[3*SEG + 2048 + j] + bih[2048 + j] + bhh[2048 + j];
  float og = gb[3072 + j] + gb[SEG + 3072 + j] + gb[2*SEG + 3072 + j] + gb[3*SEG + 3072 + j] + bih[3072 + j] + bhh[3072 + j];
  float cn = sigmoidf_(fg) * c_old[idx] + sigmoidf_(ig) * tanhf_(gg);
  float hn = sigmoidf_(og) * tanhf_(cn);
  h_out[idx] = hn;
  c_out[idx] = cn;
  x_out[idx] = x_in[idx] + hn;
}

// ---------------------------------------------------------------------------
// mel head (wave-parallel dot per output) + stop head. One block per b.
// ---------------------------------------------------------------------------
__global__ __launch_bounds__(256) void mel_stop_kernel(
    const float* __restrict__ x3, const float* __restrict__ ctx,
    const float* __restrict__ mel_w, const float* __restrict__ stop_w,
    const float* __restrict__ stop_b,
    float* __restrict__ out_mels, float* __restrict__ out_stop)
{
  __shared__ float s_x[LSTM_];
  __shared__ float s_c[INP];
  __shared__ float s_red[4];
  const int b = blockIdx.x, tid = threadIdx.x;
  const int lane = tid & 63, wave = tid >> 6;
  for (int k = tid; k < LSTM_; k += 256) s_x[k] = x3[(size_t)b * LSTM_ + k];
  for (int k = tid; k < INP; k += 256) s_c[k] = ctx[(size_t)b * INP + k];
  __syncthreads();
#pragma unroll
  for (int i = 0; i < 20; ++i) {
    int n = wave * 20 + i;
    const float* wrow = mel_w + (size_t)n * MAXR * LSTM_;
    float a = 0.f;
    for (int k = lane; k < LSTM_; k += 64) a += s_x[k] * wrow[k];
#pragma unroll
    for (int o = 32; o >= 1; o >>= 1) a += __shfl_xor(a, o);
    if (lane == 0) out_mels[(size_t)b * NMELS + n] = a;
  }
  float p = 0.f;
  for (int k = tid; k < LSTM_; k += 256) p += s_x[k] * stop_w[k];
  for (int k = tid; k < INP; k += 256) p += s_c[k] * stop_w[LSTM_ + k];
#pragma unroll
  for (int o = 32; o >= 1; o >>= 1) p += __shfl_xor(p, o);
  if (lane == 0) s_red[wave] = p;
  __syncthreads();
  if (tid == 0) {
    float t = s_red[0] + s_red[1] + s_red[2] + s_red[3] + stop_b[0];
    out_stop[b] = sigmoidf_(t);
  }
}

// ---------------------------------------------------------------------------
extern "C" void kernel_launch(void* const* d_in, const int* in_sizes, int n_in,
                              void* d_out, int out_size, void* d_ws, size_t ws_size,
                              hipStream_t stream) {
  const float* enc   = (const float*)d_in[0];
  const float* esp   = (const float*)d_in[1];
  const float* prein = (const float*)d_in[2];
  const float* ah0   = (const float*)d_in[3];
  const float* h1_0  = (const float*)d_in[4];
  const float* h2_0  = (const float*)d_in[5];
  const float* c1_0  = (const float*)d_in[6];
  const float* c2_0  = (const float*)d_in[7];
  const float* ctx0  = (const float*)d_in[8];
  const float* cum   = (const float*)d_in[9];
  const int*   chars = (const int*)d_in[10];
  const float* pw1 = (const float*)d_in[11];
  const float* pb1 = (const float*)d_in[12];
  const float* pw2 = (const float*)d_in[13];
  const float* pb2 = (const float*)d_in[14];
  const float* gwih = (const float*)d_in[15];
  const float* gwhh = (const float*)d_in[16];
  const float* gbih = (const float*)d_in[17];
  const float* gbhh = (const float*)d_in[18];
  const float* cvw = (const float*)d_in[19];
  const float* cvb = (const float*)d_in[20];
  const float* lsaL = (const float*)d_in[21];
  const float* lsaW = (const float*)d_in[22];
  const float* lsaWb = (const float*)d_in[23];
  const float* lsav = (const float*)d_in[24];
  const float* riw = (const float*)d_in[25];
  const float* rib = (const float*)d_in[26];
  const float* l1wih = (const float*)d_in[27];
  const float* l1whh = (const float*)d_in[28];
  const float* l1bih = (const float*)d_in[29];
  const float* l1bhh = (const float*)d_in[30];
  const float* l2wih = (const float*)d_in[31];
  const float* l2whh = (const float*)d_in[32];
  const float* l2bih = (const float*)d_in[33];
  const float* l2bhh = (const float*)d_in[34];
  const float* melw = (const float*)d_in[35];
  const float* stopw = (const float*)d_in[36];
  const float* stopb = (const float*)d_in[37];

  float* out = (float*)d_out;
  float* o_mels   = out;             // (256,80,1)
  float* o_scores = out + 20480;     // (256,1,400)
  float* o_attn   = out + 122880;    // (256,128)
  float* o_h1     = out + 155648;    // (256,1024)
  float* o_h2     = out + 417792;
  float* o_c1     = out + 679936;
  float* o_c2     = out + 942080;
  float* o_ctx    = out + 1204224;   // (256,512)
  float* o_stop   = out + 1335296;   // (256,1)
  float* o_cum    = out + 1335552;   // (256,400)

  float* ws = (float*)d_ws;
  float* ws_h    = ws;               // 256*256
  float* ws_pre2 = ws + 65536;       // 256*256
  float* ws_gi2  = ws + 131072;      // 2*256*384
  float* ws_pq   = ws + 327680;      // 256*128
  float* ws_u    = ws + 360448;      // 256*400
  float* ws_part = ws + 462848;      // 4*256*512
  float* ws_x    = ws + 987136;      // 256*1024
  float* ws_x2   = ws + 1249280;     // 256*1024
  float* ws_x3   = ws + 1511424;     // 256*1024
  float* ws_g4   = ws + 1773568;     // 4*256*4096

  dim3 blk(256);

  // 1-2. prenet (K=80 then K=256), relu
  gemm_bf16<<<dim3(4, 4, 1), blk, 0, stream>>>(
      prein, 80, pw1, 80, 80, nullptr, 0, nullptr, 0, 0,
      pb1, nullptr, ws_h, 256, 1, 0);
  gemm_bf16<<<dim3(4, 4, 1), blk, 0, stream>>>(
      ws_h, 256, pw2, 256, 256, nullptr, 0, nullptr, 0, 0,
      pb2, nullptr, ws_pre2, 256, 1, 0);
  // 3. gi partials: [ctx | prenet] @ w_ih^T, pair-split over grid.z
  gemm_bf16<<<dim3(6, 4, 2), blk, 0, stream>>>(
      ctx0, 512, gwih, 768, 512, ws_pre2, 256, gwih + 512, 768, 256,
      nullptr, nullptr, ws_gi2, 384, 0, 1);
  // 4. GRU tail: gh GEMV + cell + processed_query
  gru_fused_kernel<<<dim3(B_), blk, 0, stream>>>(
      ws_gi2, gwhh, gbih, gbhh, ah0, lsaW, lsaWb, o_attn, ws_pq);
  // 5. attention scores (MFMA)
  attn_score_kernel<<<dim3(2, B_), blk, 0, stream>>>(
      esp, cum, chars, cvw, cvb, lsaL, lsav, ws_pq, ws_u);
  // 6. softmax + context partials
  ctx_smax_part_kernel<<<dim3(TCH, B_), blk, 0, stream>>>(
      enc, ws_u, cum, o_scores, o_cum, ws_part);
  // 7. context reduce
  ctx_reduce_kernel<<<dim3(512), blk, 0, stream>>>(ws_part, o_ctx);
  // 8. rnn_in: [ctx | attn_hidden] @ riw^T + b
  gemm_bf16<<<dim3(16, 4, 1), blk, 0, stream>>>(
      o_ctx, 512, riw, 640, 512, o_attn, 128, riw + 512, 640, 128,
      rib, nullptr, ws_x, 1024, 0, 0);
  // 9-10. LSTM1 (K-split partials -> cell)
  gemm_bf16<<<dim3(64, 4, 4), blk, 0, stream>>>(
      ws_x, 1024, l1wih, 1024, 1024, h1_0, 1024, l1whh, 1024, 1024,
      nullptr, nullptr, ws_g4, 4096, 0, 2);
  lstm_cell_kernel<<<dim3(1024), blk, 0, stream>>>(
      ws_g4, l1bih, l1bhh, c1_0, ws_x, o_h1, o_c1, ws_x2);
  // 11-12. LSTM2
  gemm_bf16<<<dim3(64, 4, 4), blk, 0, stream>>>(
      ws_x2, 1024, l2wih, 1024, 1024, h2_0, 1024, l2whh, 1024, 1024,
      nullptr, nullptr, ws_g4, 4096, 0, 2);
  lstm_cell_kernel<<<dim3(1024), blk, 0, stream>>>(
      ws_g4, l2bih, l2bhh, c2_0, ws_x2, o_h2, o_c2, ws_x3);
  // 13. heads
  mel_stop_kernel<<<dim3(B_), blk, 0, stream>>>(
      ws_x3, o_ctx, melw, stopw, stopb, o_mels, o_stop);
}